// Round 1
// baseline (1480.270 us; speedup 1.0000x reference)
//
#include <hip/hip_runtime.h>

// Markonv: out[b,k,p] = sum_{i<16, c1<4, c2<4} x[b,p+i,c1] * x[b,p+i+1,c2] * ker[i,c1,c2,k]
// x:   [B=128, L=10000, C=4] fp32, channel-last -> x[b][t][:] is an aligned float4
// ker: [KL=16, 4, 4, K=128] fp32 -> ker[(i*16 + c1*4 + c2)*128 + k]
// out: [B=128, K=128, LOUT=9984] fp32

#define LL    10000
#define LOUT  9984
#define KL    16
#define NK    128

__global__ __launch_bounds__(256) void markonv_kernel(
    const float* __restrict__ x,
    const float* __restrict__ ker,
    float* __restrict__ out)
{
    const int b = blockIdx.y;
    const int p = blockIdx.x * 64 + (threadIdx.x & 63);        // LOUT = 156*64 exactly
    // k-group 0..3, wave-uniform (forced to SGPR so weight loads scalarize)
    const int kq = __builtin_amdgcn_readfirstlane((int)(threadIdx.x >> 6));

    const float* xb = x + (size_t)b * (LL * 4);

    float4 xc = *(const float4*)(xb + (size_t)p * 4);
    float acc[32];
    #pragma unroll
    for (int j = 0; j < 32; ++j) acc[j] = 0.0f;

    #pragma unroll 1
    for (int i = 0; i < KL; ++i) {
        float4 xn = *(const float4*)(xb + (size_t)(p + i + 1) * 4);

        // pair products pp[c1*4+c2] = x[.,p+i,c1] * x[.,p+i+1,c2]
        float pp[16];
        pp[ 0] = xc.x * xn.x;  pp[ 1] = xc.x * xn.y;
        pp[ 2] = xc.x * xn.z;  pp[ 3] = xc.x * xn.w;
        pp[ 4] = xc.y * xn.x;  pp[ 5] = xc.y * xn.y;
        pp[ 6] = xc.y * xn.z;  pp[ 7] = xc.y * xn.w;
        pp[ 8] = xc.z * xn.x;  pp[ 9] = xc.z * xn.y;
        pp[10] = xc.z * xn.z;  pp[11] = xc.z * xn.w;
        pp[12] = xc.w * xn.x;  pp[13] = xc.w * xn.y;
        pp[14] = xc.w * xn.z;  pp[15] = xc.w * xn.w;

        // wave-uniform weight base: ker[i][cc][kq*32 + j]
        const float* w = ker + (size_t)i * 16 * NK + kq * 32;

        #pragma unroll
        for (int j = 0; j < 32; ++j) {
            float s = 0.0f;
            #pragma unroll
            for (int cc = 0; cc < 16; ++cc)
                s = fmaf(pp[cc], w[cc * NK + j], s);
            acc[j] += s;
        }

        xc = xn;
    }

    float* ob = out + ((size_t)b * NK + (size_t)kq * 32) * LOUT + p;
    #pragma unroll
    for (int j = 0; j < 32; ++j)
        ob[(size_t)j * LOUT] = acc[j];
}

extern "C" void kernel_launch(void* const* d_in, const int* in_sizes, int n_in,
                              void* d_out, int out_size, void* d_ws, size_t ws_size,
                              hipStream_t stream)
{
    const float* x   = (const float*)d_in[0];
    const float* ker = (const float*)d_in[1];
    float* out       = (float*)d_out;

    const int B = in_sizes[0] / (LL * 4);   // 128
    dim3 grid(LOUT / 64, B);
    markonv_kernel<<<grid, dim3(256), 0, stream>>>(x, ker, out);
}